// Round 3
// baseline (404.123 us; speedup 1.0000x reference)
//
#include <hip/hip_runtime.h>
#include <math.h>

#define NDEV 50000
#define NTASK 100000
#define NE 1000000
#define TILE 1024
#define NB_T ((NTASK + TILE - 1) / TILE)   // 98
#define NB_D ((NDEV + TILE - 1) / TILE)    // 49

typedef unsigned int uint;

__device__ inline uint bf16rn(float f) {
    uint x = __float_as_uint(f);
    return (x + 0x7fffu + ((x >> 16) & 1u)) >> 16;
}
__device__ inline uint bf16pair(float a, float b) {
    return bf16rn(a) | (bf16rn(b) << 16);
}

// ---------------- weight prep: [W_src | fold(W_src,a_src) | fold(W_dst_other,a_dst_other)]
__global__ void prep_weights(
    const float* __restrict__ W1a_src, const float* __restrict__ a1a_src,
    const float* __restrict__ W1a_dst, const float* __restrict__ a1a_dst,
    const float* __restrict__ W1b_src, const float* __restrict__ a1b_src,
    const float* __restrict__ W1b_dst, const float* __restrict__ a1b_dst,
    const float* __restrict__ W2a_src, const float* __restrict__ a2a_src,
    const float* __restrict__ W2a_dst, const float* __restrict__ a2a_dst,
    const float* __restrict__ W2b_src, const float* __restrict__ a2b_src,
    const float* __restrict__ W2b_dst, const float* __restrict__ a2b_dst,
    float* __restrict__ Wc_dev1, float* __restrict__ Wc_task1,
    float* __restrict__ Wc_dev2, float* __restrict__ Wc_task2)
{
    int f = threadIdx.x;
    if (f >= 64) return;
    for (int o = 0; o < 64; ++o) Wc_dev1[f*72 + o] = W1a_src[f*64 + o];
    for (int h = 0; h < 4; ++h) {
        float s = 0.f;
        for (int c = 0; c < 16; ++c) s += W1a_src[f*64 + h*16 + c] * a1a_src[h*16 + c];
        Wc_dev1[f*72 + 64 + h] = s;
    }
    for (int h = 0; h < 4; ++h) {
        float s = 0.f;
        for (int c = 0; c < 16; ++c) s += W1b_dst[f*64 + h*16 + c] * a1b_dst[h*16 + c];
        Wc_dev1[f*72 + 68 + h] = s;
    }
    for (int o = 0; o < 64; ++o) Wc_task1[f*72 + o] = W1b_src[f*64 + o];
    for (int h = 0; h < 4; ++h) {
        float s = 0.f;
        for (int c = 0; c < 16; ++c) s += W1b_src[f*64 + h*16 + c] * a1b_src[h*16 + c];
        Wc_task1[f*72 + 64 + h] = s;
    }
    for (int h = 0; h < 4; ++h) {
        float s = 0.f;
        for (int c = 0; c < 16; ++c) s += W1a_dst[f*64 + h*16 + c] * a1a_dst[h*16 + c];
        Wc_task1[f*72 + 68 + h] = s;
    }
    for (int o = 0; o < 32; ++o) Wc_dev2[f*36 + o] = W2a_src[f*32 + o];
    { float s = 0.f; for (int c = 0; c < 32; ++c) s += W2a_src[f*32+c]*a2a_src[c]; Wc_dev2[f*36+32] = s; }
    { float s = 0.f; for (int c = 0; c < 32; ++c) s += W2b_dst[f*32+c]*a2b_dst[c]; Wc_dev2[f*36+33] = s; }
    Wc_dev2[f*36+34] = 0.f; Wc_dev2[f*36+35] = 0.f;
    for (int o = 0; o < 32; ++o) Wc_task2[f*36 + o] = W2b_src[f*32 + o];
    { float s = 0.f; for (int c = 0; c < 32; ++c) s += W2b_src[f*32+c]*a2b_src[c]; Wc_task2[f*36+32] = s; }
    { float s = 0.f; for (int c = 0; c < 32; ++c) s += W2a_dst[f*32+c]*a2a_dst[c]; Wc_task2[f*36+33] = s; }
    Wc_task2[f*36+34] = 0.f; Wc_task2[f*36+35] = 0.f;
}

// ---------------- dense transform, both node types in one launch; hs written as packed bf16
template<int COP, int CHS, int CA>
__global__ __launch_bounds__(256) void gemm_both(
    const float* __restrict__ XA, int NA, const float* __restrict__ WcA,
    uint* __restrict__ hsA, float* __restrict__ alsA, float* __restrict__ aldA,
    const float* __restrict__ XB, int NB, const float* __restrict__ WcB,
    uint* __restrict__ hsB, float* __restrict__ alsB, float* __restrict__ aldB)
{
    int nbA = (NA + 255) / 256;
    const float* X; const float* Wc; uint* hs; float* als; float* ald; int N, n0;
    if ((int)blockIdx.x < nbA) { X=XA; Wc=WcA; hs=hsA; als=alsA; ald=aldA; N=NA; n0=blockIdx.x*256; }
    else { X=XB; Wc=WcB; hs=hsB; als=alsB; ald=aldB; N=NB; n0=((int)blockIdx.x-nbA)*256; }

    __shared__ __align__(16) float w[64 * COP];
    for (int i = threadIdx.x; i < 64 * COP; i += 256) w[i] = Wc[i];
    __syncthreads();
    int n = n0 + threadIdx.x;
    if (n >= N) return;

    const float4* X4 = reinterpret_cast<const float4*>(X + (size_t)n * 64);
    float4 acc[CHS/4];
    #pragma unroll
    for (int j = 0; j < CHS/4; ++j) acc[j] = make_float4(0.f, 0.f, 0.f, 0.f);
    float aacc[2*CA];
    #pragma unroll
    for (int j = 0; j < 2*CA; ++j) aacc[j] = 0.f;

    for (int k16 = 0; k16 < 4; ++k16) {
        float4 xv4[4];
        #pragma unroll
        for (int q = 0; q < 4; ++q) xv4[q] = X4[k16*4 + q];
        float xs[16];
        #pragma unroll
        for (int q = 0; q < 4; ++q) {
            xs[4*q+0] = xv4[q].x; xs[4*q+1] = xv4[q].y;
            xs[4*q+2] = xv4[q].z; xs[4*q+3] = xv4[q].w;
        }
        #pragma unroll
        for (int kk = 0; kk < 16; ++kk) {
            int k = k16*16 + kk;
            float xv = xs[kk];
            const float* wr = &w[k * COP];
            #pragma unroll
            for (int j = 0; j < CHS/4; ++j) {
                float4 wv = *reinterpret_cast<const float4*>(wr + 4*j);
                acc[j].x += xv * wv.x; acc[j].y += xv * wv.y;
                acc[j].z += xv * wv.z; acc[j].w += xv * wv.w;
            }
            #pragma unroll
            for (int j = 0; j < 2*CA; ++j) aacc[j] += xv * wr[CHS + j];
        }
    }
    // pack hs row to bf16 pairs: pk[p] = channels {2p, 2p+1}
    uint pk[CHS/2];
    #pragma unroll
    for (int j = 0; j < CHS/4; ++j) {
        pk[2*j]   = bf16pair(acc[j].x, acc[j].y);
        pk[2*j+1] = bf16pair(acc[j].z, acc[j].w);
    }
    uint4* hrow = reinterpret_cast<uint4*>(hs + (size_t)n * (CHS/2));
    #pragma unroll
    for (int j = 0; j < CHS/8; ++j)
        hrow[j] = make_uint4(pk[4*j], pk[4*j+1], pk[4*j+2], pk[4*j+3]);
    #pragma unroll
    for (int j = 0; j < CA; ++j) als[(size_t)n*CA + j] = aacc[j];
    #pragma unroll
    for (int j = 0; j < CA; ++j) ald[(size_t)n*CA + j] = aacc[CA + j];
}

// ---------------- CSR build: single atomic pass recording per-edge rank
__global__ void edge_rank(const int* __restrict__ wdst, const int* __restrict__ bdst,
                          int* __restrict__ cnt_task, int* __restrict__ cnt_dev,
                          int* __restrict__ rank_w, int* __restrict__ rank_b)
{
    int i = blockIdx.x * blockDim.x + threadIdx.x;
    if (i < NE) rank_w[i] = atomicAdd(&cnt_task[wdst[i]], 1);
    else { int j = i - NE; if (j < NE) rank_b[j] = atomicAdd(&cnt_dev[bdst[j]], 1); }
}

__global__ void scan_tiles(const int* __restrict__ cnt_task, const int* __restrict__ cnt_dev,
                           int* __restrict__ offs_task, int* __restrict__ offs_dev,
                           int* __restrict__ partials)
{
    __shared__ int sm[256];
    int b = blockIdx.x, t = threadIdx.x;
    const int* cnt; int* offs; int n; int tile;
    if (b < NB_T) { cnt = cnt_task; offs = offs_task; n = NTASK; tile = b; }
    else          { cnt = cnt_dev;  offs = offs_dev;  n = NDEV;  tile = b - NB_T; }
    int base = tile * TILE;
    int v[4]; int s = 0;
    #pragma unroll
    for (int k = 0; k < 4; ++k) { int idx = base + t*4 + k; v[k] = (idx < n) ? cnt[idx] : 0; s += v[k]; }
    sm[t] = s; __syncthreads();
    int x = s;
    for (int off = 1; off < 256; off <<= 1) {
        int y = (t >= off) ? sm[t - off] : 0;
        __syncthreads();
        x += y; sm[t] = x;
        __syncthreads();
    }
    int run = x - s;
    #pragma unroll
    for (int k = 0; k < 4; ++k) { int idx = base + t*4 + k; if (idx < n) offs[idx] = run; run += v[k]; }
    if (t == 255) partials[b] = x;
}

__device__ void scan_small(int* p, int n, int* sm)
{
    int t = threadIdx.x;
    int v = (t < n) ? p[t] : 0;
    sm[t] = v; __syncthreads();
    int x = v;
    for (int off = 1; off < 256; off <<= 1) {
        int y = (t >= off) ? sm[t - off] : 0;
        __syncthreads();
        x += y; sm[t] = x;
        __syncthreads();
    }
    if (t < n) p[t] = x - v;
    __syncthreads();
}

__global__ void scan_partials_k(int* __restrict__ partials)
{
    __shared__ int sm[256];
    scan_small(partials, NB_T, sm);
    scan_small(partials + NB_T, NB_D, sm);
}

__global__ void scan_add(int* __restrict__ offs_task, int* __restrict__ offs_dev,
                         const int* __restrict__ partials)
{
    int b = blockIdx.x;
    int add = partials[b];
    int* offs; int n; int tile;
    if (b < NB_T) { offs = offs_task; n = NTASK; tile = b; }
    else          { offs = offs_dev;  n = NDEV;  tile = b - NB_T; }
    int base = tile * TILE;
    for (int idx = base + threadIdx.x; idx < base + TILE && idx < n; idx += 256)
        offs[idx] += add;
    if (b == 0 && threadIdx.x == 0) { offs_task[NTASK] = NE; offs_dev[NDEV] = NE; }
}

// non-atomic scatter using precomputed rank
__global__ void edge_fill2(const int* __restrict__ wsrc, const int* __restrict__ wdst,
                           const int* __restrict__ bsrc, const int* __restrict__ bdst,
                           const int* __restrict__ offs_task, const int* __restrict__ offs_dev,
                           const int* __restrict__ rank_w, const int* __restrict__ rank_b,
                           int* __restrict__ s_w, int* __restrict__ s_b)
{
    int i = blockIdx.x * blockDim.x + threadIdx.x;
    if (i < NE) s_w[offs_task[wdst[i]] + rank_w[i]] = wsrc[i];
    else { int j = i - NE; if (j < NE) s_b[offs_dev[bdst[j]] + rank_b[j]] = bsrc[j]; }
}

// ---------------- layer-1 aggregation: wave per dst, HALF-wave per edge, bf16 hs
// lanes: sub = lane>>5 (edge parity), cl = lane&31 (channel pair {2cl,2cl+1}), h = cl>>3
__global__ __launch_bounds__(256) void gat_agg_l1(
    const int* __restrict__ offs_t, const int* __restrict__ srcs_t,
    const float* __restrict__ als_d_, const float* __restrict__ ald_t,
    const uint* __restrict__ hs_d_, const float* __restrict__ bias_a, float* __restrict__ out_t,
    const int* __restrict__ offs_d, const int* __restrict__ srcs_d,
    const float* __restrict__ als_t, const float* __restrict__ ald_d,
    const uint* __restrict__ hs_t, const float* __restrict__ bias_b, float* __restrict__ out_d)
{
    const int nbT = (NTASK + 3) / 4;
    int wave = threadIdx.x >> 6, lane = threadIdx.x & 63;
    const int* offs; const int* srcs; const float* als; const float* ald;
    const uint* hs; const float* bias; float* out; int Nd, d;
    if ((int)blockIdx.x < nbT) {
        offs = offs_t; srcs = srcs_t; als = als_d_; ald = ald_t; hs = hs_d_;
        bias = bias_a; out = out_t; Nd = NTASK; d = blockIdx.x * 4 + wave;
    } else {
        offs = offs_d; srcs = srcs_d; als = als_t; ald = ald_d; hs = hs_t;
        bias = bias_b; out = out_d; Nd = NDEV; d = ((int)blockIdx.x - nbT) * 4 + wave;
    }
    if (d >= Nd) return;
    int sub = lane >> 5;
    int cl  = lane & 31;
    int h   = cl >> 3;
    float aldv = ald[d * 4 + h];
    int beg = __builtin_amdgcn_readfirstlane(offs[d]);
    int end = __builtin_amdgcn_readfirstlane(offs[d + 1]);
    float den = 0.f, accL = 0.f, accH = 0.f;
    int nIt = (end - beg + 1) >> 1;
    for (int it = 0; it < nIt; ++it) {
        int i = beg + (it << 1) + sub;
        bool valid = i < end;
        int s = srcs[valid ? i : beg];
        float e = als[s * 4 + h] + aldv;
        e = fmaxf(e, 0.2f * e);
        float wgt = valid ? __expf(e) : 0.f;
        uint pv = hs[s * 32 + cl];
        float lo = __uint_as_float(pv << 16);
        float hi = __uint_as_float(pv & 0xffff0000u);
        den  += wgt;
        accL += wgt * lo;
        accH += wgt * hi;
    }
    den  += __shfl_xor(den, 32, 64);
    accL += __shfl_xor(accL, 32, 64);
    accH += __shfl_xor(accH, 32, 64);
    if (sub == 0) {
        float inv = 1.f / (den + 1e-16f);
        float o0 = fmaxf(accL * inv + bias[2*cl],     0.f);
        float o1 = fmaxf(accH * inv + bias[2*cl + 1], 0.f);
        *reinterpret_cast<float2*>(&out[(size_t)d * 64 + 2*cl]) = make_float2(o0, o1);
    }
}

// ---------------- layer-2 aggregation: wave per dst, QUARTER-wave per edge, bf16 hs
// lanes: sub = lane>>4 (0..3), cl = lane&15 (channel pair {2cl,2cl+1} of 32), single head
__global__ __launch_bounds__(256) void gat_agg_l2(
    const int* __restrict__ offs_t, const int* __restrict__ srcs_t,
    const float* __restrict__ als_d_, const float* __restrict__ ald_t,
    const uint* __restrict__ hs_d_, const float* __restrict__ bias_a, float* __restrict__ out_t,
    const int* __restrict__ offs_d, const int* __restrict__ srcs_d,
    const float* __restrict__ als_t, const float* __restrict__ ald_d,
    const uint* __restrict__ hs_t, const float* __restrict__ bias_b, float* __restrict__ out_d)
{
    const int nbT = (NTASK + 3) / 4;
    int wave = threadIdx.x >> 6, lane = threadIdx.x & 63;
    const int* offs; const int* srcs; const float* als; const float* ald;
    const uint* hs; const float* bias; float* out; int Nd, d;
    if ((int)blockIdx.x < nbT) {
        offs = offs_t; srcs = srcs_t; als = als_d_; ald = ald_t; hs = hs_d_;
        bias = bias_a; out = out_t; Nd = NTASK; d = blockIdx.x * 4 + wave;
    } else {
        offs = offs_d; srcs = srcs_d; als = als_t; ald = ald_d; hs = hs_t;
        bias = bias_b; out = out_d; Nd = NDEV; d = ((int)blockIdx.x - nbT) * 4 + wave;
    }
    if (d >= Nd) return;
    int sub = lane >> 4;
    int cl  = lane & 15;
    float aldv = ald[d];
    int beg = __builtin_amdgcn_readfirstlane(offs[d]);
    int end = __builtin_amdgcn_readfirstlane(offs[d + 1]);
    float den = 0.f, accL = 0.f, accH = 0.f;
    int nIt = (end - beg + 3) >> 2;
    for (int it = 0; it < nIt; ++it) {
        int i = beg + (it << 2) + sub;
        bool valid = i < end;
        int s = srcs[valid ? i : beg];
        float e = als[s] + aldv;
        e = fmaxf(e, 0.2f * e);
        float wgt = valid ? __expf(e) : 0.f;
        uint pv = hs[s * 16 + cl];
        float lo = __uint_as_float(pv << 16);
        float hi = __uint_as_float(pv & 0xffff0000u);
        den  += wgt;
        accL += wgt * lo;
        accH += wgt * hi;
    }
    den  += __shfl_xor(den, 16, 64);  den  += __shfl_xor(den, 32, 64);
    accL += __shfl_xor(accL, 16, 64); accL += __shfl_xor(accL, 32, 64);
    accH += __shfl_xor(accH, 16, 64); accH += __shfl_xor(accH, 32, 64);
    if (lane < 16) {
        float inv = 1.f / (den + 1e-16f);
        float o0 = fmaxf(accL * inv + bias[2*cl],     0.f);
        float o1 = fmaxf(accH * inv + bias[2*cl + 1], 0.f);
        *reinterpret_cast<float2*>(&out[(size_t)d * 32 + 2*cl]) = make_float2(o0, o1);
    }
}

// ---------------- launch
extern "C" void kernel_launch(void* const* d_in, const int* in_sizes, int n_in,
                              void* d_out, int out_size, void* d_ws, size_t ws_size,
                              hipStream_t stream)
{
    const float* x_dev   = (const float*)d_in[0];
    const float* x_task  = (const float*)d_in[1];
    const int* writes_src = (const int*)d_in[2];
    const int* writes_dst = (const int*)d_in[3];
    const int* wb_src     = (const int*)d_in[4];
    const int* wb_dst     = (const int*)d_in[5];
    const float* W1a_src = (const float*)d_in[6],  *W1a_dst = (const float*)d_in[7];
    const float* a1a_src = (const float*)d_in[8],  *a1a_dst = (const float*)d_in[9];
    const float* b1a     = (const float*)d_in[10];
    const float* W1b_src = (const float*)d_in[11], *W1b_dst = (const float*)d_in[12];
    const float* a1b_src = (const float*)d_in[13], *a1b_dst = (const float*)d_in[14];
    const float* b1b     = (const float*)d_in[15];
    const float* W2a_src = (const float*)d_in[16], *W2a_dst = (const float*)d_in[17];
    const float* a2a_src = (const float*)d_in[18], *a2a_dst = (const float*)d_in[19];
    const float* b2a     = (const float*)d_in[20];
    const float* W2b_src = (const float*)d_in[21], *W2b_dst = (const float*)d_in[22];
    const float* a2b_src = (const float*)d_in[23], *a2b_dst = (const float*)d_in[24];
    const float* b2b     = (const float*)d_in[25];

    float* out_dev2  = (float*)d_out;
    float* out_task2 = (float*)d_out + (size_t)NDEV * 32;

    char* ws = (char*)d_ws;
    size_t off = 0;
    auto take = [&](size_t bytes) -> void* {
        off = (off + 255) & ~(size_t)255;
        void* p = ws + off; off += bytes; return p;
    };
    int* s_w       = (int*)take((size_t)NE * 4);
    int* s_b       = (int*)take((size_t)NE * 4);
    int* offs_task = (int*)take((size_t)(NTASK + 1) * 4);
    int* offs_dev  = (int*)take((size_t)(NDEV + 1) * 4);
    int* cnt_task  = (int*)take((size_t)(NTASK + NDEV) * 4);
    int* cnt_dev   = cnt_task + NTASK;
    int* partials  = (int*)take(256 * 4);
    float* Wc_dev1  = (float*)take(64 * 72 * 4);
    float* Wc_task1 = (float*)take(64 * 72 * 4);
    float* Wc_dev2  = (float*)take(64 * 36 * 4);
    float* Wc_task2 = (float*)take(64 * 36 * 4);
    uint* hs_dev    = (uint*)take((size_t)NDEV * 32 * 4);    // bf16-packed, 64ch l1 / 32ch l2
    float* als_dev  = (float*)take((size_t)NDEV * 4 * 4);
    float* aldx_dev = (float*)take((size_t)NDEV * 4 * 4);
    uint* hs_task   = (uint*)take((size_t)NTASK * 32 * 4);
    float* als_task = (float*)take((size_t)NTASK * 4 * 4);
    float* aldx_task= (float*)take((size_t)NTASK * 4 * 4);
    float* x_task1  = (float*)take((size_t)NTASK * 64 * 4);
    float* x_dev1   = (float*)take((size_t)NDEV * 64 * 4);
    // rank arrays alias x_dev1 (12.8MB >= 8MB): written by edge_rank, consumed by
    // edge_fill2, both strictly before gat_agg_l1 writes x_dev1 (in-order stream).
    int* rank_w = (int*)x_dev1;
    int* rank_b = rank_w + NE;
    (void)ws_size; (void)n_in; (void)in_sizes; (void)out_size;

    hipMemsetAsync(cnt_task, 0, (size_t)(NTASK + NDEV) * 4, stream);

    prep_weights<<<1, 64, 0, stream>>>(
        W1a_src, a1a_src, W1a_dst, a1a_dst, W1b_src, a1b_src, W1b_dst, a1b_dst,
        W2a_src, a2a_src, W2a_dst, a2a_dst, W2b_src, a2b_src, W2b_dst, a2b_dst,
        Wc_dev1, Wc_task1, Wc_dev2, Wc_task2);

    // CSR build (shared by both layers)
    int eg = (2 * NE + 255) / 256;
    edge_rank<<<eg, 256, 0, stream>>>(writes_dst, wb_dst, cnt_task, cnt_dev, rank_w, rank_b);
    scan_tiles<<<NB_T + NB_D, 256, 0, stream>>>(cnt_task, cnt_dev, offs_task, offs_dev, partials);
    scan_partials_k<<<1, 256, 0, stream>>>(partials);
    scan_add<<<NB_T + NB_D, 256, 0, stream>>>(offs_task, offs_dev, partials);
    edge_fill2<<<eg, 256, 0, stream>>>(writes_src, writes_dst, wb_src, wb_dst,
                                       offs_task, offs_dev, rank_w, rank_b, s_w, s_b);

    // layer 1 transforms (both node types, one launch)
    int nb1 = (NDEV + 255) / 256 + (NTASK + 255) / 256;
    gemm_both<72, 64, 4><<<nb1, 256, 0, stream>>>(
        x_dev, NDEV, Wc_dev1, hs_dev, als_dev, aldx_dev,
        x_task, NTASK, Wc_task1, hs_task, als_task, aldx_task);

    // layer 1 aggregation (both directions, one launch)
    int nbagg = (NTASK + 3) / 4 + (NDEV + 3) / 4;
    gat_agg_l1<<<nbagg, 256, 0, stream>>>(
        offs_task, s_w, als_dev, aldx_task, hs_dev, b1a, x_task1,
        offs_dev, s_b, als_task, aldx_dev, hs_task, b1b, x_dev1);

    // layer 2 transforms
    gemm_both<36, 32, 1><<<nb1, 256, 0, stream>>>(
        x_dev1, NDEV, Wc_dev2, hs_dev, als_dev, aldx_dev,
        x_task1, NTASK, Wc_task2, hs_task, als_task, aldx_task);

    // layer 2 aggregation -> final outputs
    gat_agg_l2<<<nbagg, 256, 0, stream>>>(
        offs_task, s_w, als_dev, aldx_task, hs_dev, b2a, out_task2,
        offs_dev, s_b, als_task, aldx_dev, hs_task, b2b, out_dev2);
}

// Round 4
// 346.731 us; speedup vs baseline: 1.1655x; 1.1655x over previous
//
#include <hip/hip_runtime.h>
#include <math.h>

#define NDEV 50000
#define NTASK 100000
#define NE 1000000
#define TILE 1024
#define NB_T ((NTASK + TILE - 1) / TILE)   // 98
#define NB_D ((NDEV + TILE - 1) / TILE)    // 49

typedef unsigned int uint;

__device__ inline uint bf16rn(float f) {
    uint x = __float_as_uint(f);
    return (x + 0x7fffu + ((x >> 16) & 1u)) >> 16;
}
__device__ inline uint bf16pair(float a, float b) {
    return bf16rn(a) | (bf16rn(b) << 16);
}

// ---------------- weight prep: [W_src | fold(W_src,a_src) | fold(W_dst_other,a_dst_other)]
__global__ void prep_weights(
    const float* __restrict__ W1a_src, const float* __restrict__ a1a_src,
    const float* __restrict__ W1a_dst, const float* __restrict__ a1a_dst,
    const float* __restrict__ W1b_src, const float* __restrict__ a1b_src,
    const float* __restrict__ W1b_dst, const float* __restrict__ a1b_dst,
    const float* __restrict__ W2a_src, const float* __restrict__ a2a_src,
    const float* __restrict__ W2a_dst, const float* __restrict__ a2a_dst,
    const float* __restrict__ W2b_src, const float* __restrict__ a2b_src,
    const float* __restrict__ W2b_dst, const float* __restrict__ a2b_dst,
    float* __restrict__ Wc_dev1, float* __restrict__ Wc_task1,
    float* __restrict__ Wc_dev2, float* __restrict__ Wc_task2)
{
    int f = threadIdx.x;
    if (f >= 64) return;
    for (int o = 0; o < 64; ++o) Wc_dev1[f*72 + o] = W1a_src[f*64 + o];
    for (int h = 0; h < 4; ++h) {
        float s = 0.f;
        for (int c = 0; c < 16; ++c) s += W1a_src[f*64 + h*16 + c] * a1a_src[h*16 + c];
        Wc_dev1[f*72 + 64 + h] = s;
    }
    for (int h = 0; h < 4; ++h) {
        float s = 0.f;
        for (int c = 0; c < 16; ++c) s += W1b_dst[f*64 + h*16 + c] * a1b_dst[h*16 + c];
        Wc_dev1[f*72 + 68 + h] = s;
    }
    for (int o = 0; o < 64; ++o) Wc_task1[f*72 + o] = W1b_src[f*64 + o];
    for (int h = 0; h < 4; ++h) {
        float s = 0.f;
        for (int c = 0; c < 16; ++c) s += W1b_src[f*64 + h*16 + c] * a1b_src[h*16 + c];
        Wc_task1[f*72 + 64 + h] = s;
    }
    for (int h = 0; h < 4; ++h) {
        float s = 0.f;
        for (int c = 0; c < 16; ++c) s += W1a_dst[f*64 + h*16 + c] * a1a_dst[h*16 + c];
        Wc_task1[f*72 + 68 + h] = s;
    }
    for (int o = 0; o < 32; ++o) Wc_dev2[f*36 + o] = W2a_src[f*32 + o];
    { float s = 0.f; for (int c = 0; c < 32; ++c) s += W2a_src[f*32+c]*a2a_src[c]; Wc_dev2[f*36+32] = s; }
    { float s = 0.f; for (int c = 0; c < 32; ++c) s += W2b_dst[f*32+c]*a2b_dst[c]; Wc_dev2[f*36+33] = s; }
    Wc_dev2[f*36+34] = 0.f; Wc_dev2[f*36+35] = 0.f;
    for (int o = 0; o < 32; ++o) Wc_task2[f*36 + o] = W2b_src[f*32 + o];
    { float s = 0.f; for (int c = 0; c < 32; ++c) s += W2b_src[f*32+c]*a2b_src[c]; Wc_task2[f*36+32] = s; }
    { float s = 0.f; for (int c = 0; c < 32; ++c) s += W2a_dst[f*32+c]*a2a_dst[c]; Wc_task2[f*36+33] = s; }
    Wc_task2[f*36+34] = 0.f; Wc_task2[f*36+35] = 0.f;
}

// ---------------- dense transform, both node types in one launch; hs written as packed bf16
template<int COP, int CHS, int CA>
__global__ __launch_bounds__(256) void gemm_both(
    const float* __restrict__ XA, int NA, const float* __restrict__ WcA,
    uint* __restrict__ hsA, float* __restrict__ alsA, float* __restrict__ aldA,
    const float* __restrict__ XB, int NB, const float* __restrict__ WcB,
    uint* __restrict__ hsB, float* __restrict__ alsB, float* __restrict__ aldB)
{
    int nbA = (NA + 255) / 256;
    const float* X; const float* Wc; uint* hs; float* als; float* ald; int N, n0;
    if ((int)blockIdx.x < nbA) { X=XA; Wc=WcA; hs=hsA; als=alsA; ald=aldA; N=NA; n0=blockIdx.x*256; }
    else { X=XB; Wc=WcB; hs=hsB; als=alsB; ald=aldB; N=NB; n0=((int)blockIdx.x-nbA)*256; }

    __shared__ __align__(16) float w[64 * COP];
    for (int i = threadIdx.x; i < 64 * COP; i += 256) w[i] = Wc[i];
    __syncthreads();
    int n = n0 + threadIdx.x;
    if (n >= N) return;

    const float4* X4 = reinterpret_cast<const float4*>(X + (size_t)n * 64);
    float4 acc[CHS/4];
    #pragma unroll
    for (int j = 0; j < CHS/4; ++j) acc[j] = make_float4(0.f, 0.f, 0.f, 0.f);
    float aacc[2*CA];
    #pragma unroll
    for (int j = 0; j < 2*CA; ++j) aacc[j] = 0.f;

    for (int k16 = 0; k16 < 4; ++k16) {
        float4 xv4[4];
        #pragma unroll
        for (int q = 0; q < 4; ++q) xv4[q] = X4[k16*4 + q];
        float xs[16];
        #pragma unroll
        for (int q = 0; q < 4; ++q) {
            xs[4*q+0] = xv4[q].x; xs[4*q+1] = xv4[q].y;
            xs[4*q+2] = xv4[q].z; xs[4*q+3] = xv4[q].w;
        }
        #pragma unroll
        for (int kk = 0; kk < 16; ++kk) {
            int k = k16*16 + kk;
            float xv = xs[kk];
            const float* wr = &w[k * COP];
            #pragma unroll
            for (int j = 0; j < CHS/4; ++j) {
                float4 wv = *reinterpret_cast<const float4*>(wr + 4*j);
                acc[j].x += xv * wv.x; acc[j].y += xv * wv.y;
                acc[j].z += xv * wv.z; acc[j].w += xv * wv.w;
            }
            #pragma unroll
            for (int j = 0; j < 2*CA; ++j) aacc[j] += xv * wr[CHS + j];
        }
    }
    uint pk[CHS/2];
    #pragma unroll
    for (int j = 0; j < CHS/4; ++j) {
        pk[2*j]   = bf16pair(acc[j].x, acc[j].y);
        pk[2*j+1] = bf16pair(acc[j].z, acc[j].w);
    }
    uint4* hrow = reinterpret_cast<uint4*>(hs + (size_t)n * (CHS/2));
    #pragma unroll
    for (int j = 0; j < CHS/8; ++j)
        hrow[j] = make_uint4(pk[4*j], pk[4*j+1], pk[4*j+2], pk[4*j+3]);
    #pragma unroll
    for (int j = 0; j < CA; ++j) als[(size_t)n*CA + j] = aacc[j];
    #pragma unroll
    for (int j = 0; j < CA; ++j) ald[(size_t)n*CA + j] = aacc[CA + j];
}

// ---------------- CSR build: single atomic pass recording per-edge rank
__global__ void edge_rank(const int* __restrict__ wdst, const int* __restrict__ bdst,
                          int* __restrict__ cnt_task, int* __restrict__ cnt_dev,
                          int* __restrict__ rank_w, int* __restrict__ rank_b)
{
    int i = blockIdx.x * blockDim.x + threadIdx.x;
    if (i < NE) rank_w[i] = atomicAdd(&cnt_task[wdst[i]], 1);
    else { int j = i - NE; if (j < NE) rank_b[j] = atomicAdd(&cnt_dev[bdst[j]], 1); }
}

__global__ void scan_tiles(const int* __restrict__ cnt_task, const int* __restrict__ cnt_dev,
                           int* __restrict__ offs_task, int* __restrict__ offs_dev,
                           int* __restrict__ partials)
{
    __shared__ int sm[256];
    int b = blockIdx.x, t = threadIdx.x;
    const int* cnt; int* offs; int n; int tile;
    if (b < NB_T) { cnt = cnt_task; offs = offs_task; n = NTASK; tile = b; }
    else          { cnt = cnt_dev;  offs = offs_dev;  n = NDEV;  tile = b - NB_T; }
    int base = tile * TILE;
    int v[4]; int s = 0;
    #pragma unroll
    for (int k = 0; k < 4; ++k) { int idx = base + t*4 + k; v[k] = (idx < n) ? cnt[idx] : 0; s += v[k]; }
    sm[t] = s; __syncthreads();
    int x = s;
    for (int off = 1; off < 256; off <<= 1) {
        int y = (t >= off) ? sm[t - off] : 0;
        __syncthreads();
        x += y; sm[t] = x;
        __syncthreads();
    }
    int run = x - s;
    #pragma unroll
    for (int k = 0; k < 4; ++k) { int idx = base + t*4 + k; if (idx < n) offs[idx] = run; run += v[k]; }
    if (t == 255) partials[b] = x;
}

__device__ void scan_small(int* p, int n, int* sm)
{
    int t = threadIdx.x;
    int v = (t < n) ? p[t] : 0;
    sm[t] = v; __syncthreads();
    int x = v;
    for (int off = 1; off < 256; off <<= 1) {
        int y = (t >= off) ? sm[t - off] : 0;
        __syncthreads();
        x += y; sm[t] = x;
        __syncthreads();
    }
    if (t < n) p[t] = x - v;
    __syncthreads();
}

__global__ void scan_partials_k(int* __restrict__ partials)
{
    __shared__ int sm[256];
    scan_small(partials, NB_T, sm);
    scan_small(partials + NB_T, NB_D, sm);
}

__global__ void scan_add(int* __restrict__ offs_task, int* __restrict__ offs_dev,
                         const int* __restrict__ partials)
{
    int b = blockIdx.x;
    int add = partials[b];
    int* offs; int n; int tile;
    if (b < NB_T) { offs = offs_task; n = NTASK; tile = b; }
    else          { offs = offs_dev;  n = NDEV;  tile = b - NB_T; }
    int base = tile * TILE;
    for (int idx = base + threadIdx.x; idx < base + TILE && idx < n; idx += 256)
        offs[idx] += add;
    if (b == 0 && threadIdx.x == 0) { offs_task[NTASK] = NE; offs_dev[NDEV] = NE; }
}

// non-atomic scatter using precomputed rank
__global__ void edge_fill2(const int* __restrict__ wsrc, const int* __restrict__ wdst,
                           const int* __restrict__ bsrc, const int* __restrict__ bdst,
                           const int* __restrict__ offs_task, const int* __restrict__ offs_dev,
                           const int* __restrict__ rank_w, const int* __restrict__ rank_b,
                           int* __restrict__ s_w, int* __restrict__ s_b)
{
    int i = blockIdx.x * blockDim.x + threadIdx.x;
    if (i < NE) s_w[offs_task[wdst[i]] + rank_w[i]] = wsrc[i];
    else { int j = i - NE; if (j < NE) s_b[offs_dev[bdst[j]] + rank_b[j]] = bsrc[j]; }
}

// ---------------- layer-1 aggregation: wave per dst, half-wave per edge,
// TWO independent edge-chains per lane (4 edges in flight per wave).
// lanes: sub = lane>>5 (edge slot), cl = lane&31 (dword = ch pair {2cl,2cl+1}), h = cl>>3
__global__ __launch_bounds__(256) void gat_agg_l1(
    const int* __restrict__ offs_t, const int* __restrict__ srcs_t,
    const float* __restrict__ als_d_, const float* __restrict__ ald_t,
    const uint* __restrict__ hs_d_, const float* __restrict__ bias_a, float* __restrict__ out_t,
    const int* __restrict__ offs_d, const int* __restrict__ srcs_d,
    const float* __restrict__ als_t, const float* __restrict__ ald_d,
    const uint* __restrict__ hs_t, const float* __restrict__ bias_b, float* __restrict__ out_d)
{
    const int nbT = (NTASK + 3) / 4;
    int wave = threadIdx.x >> 6, lane = threadIdx.x & 63;
    const int* offs; const int* srcs; const float* als; const float* ald;
    const uint* hs; const float* bias; float* out; int Nd, d;
    if ((int)blockIdx.x < nbT) {
        offs = offs_t; srcs = srcs_t; als = als_d_; ald = ald_t; hs = hs_d_;
        bias = bias_a; out = out_t; Nd = NTASK; d = blockIdx.x * 4 + wave;
    } else {
        offs = offs_d; srcs = srcs_d; als = als_t; ald = ald_d; hs = hs_t;
        bias = bias_b; out = out_d; Nd = NDEV; d = ((int)blockIdx.x - nbT) * 4 + wave;
    }
    if (d >= Nd) return;
    int sub = lane >> 5;
    int cl  = lane & 31;
    int h   = cl >> 3;
    float aldv = ald[d * 4 + h];
    int beg = __builtin_amdgcn_readfirstlane(offs[d]);
    int end = __builtin_amdgcn_readfirstlane(offs[d + 1]);
    float denA = 0.f, aLA = 0.f, aHA = 0.f;
    float denB = 0.f, aLB = 0.f, aHB = 0.f;
    for (int i0 = beg + sub; i0 < end; i0 += 4) {
        int iB = i0 + 2;
        bool vB = iB < end;
        int sA = srcs[i0];
        int sB = srcs[vB ? iB : beg];
        float eA = als[sA * 4 + h] + aldv; eA = fmaxf(eA, 0.2f * eA);
        float eB = als[sB * 4 + h] + aldv; eB = fmaxf(eB, 0.2f * eB);
        float wA = __expf(eA);
        float wB = vB ? __expf(eB) : 0.f;
        uint pA = hs[sA * 32 + cl];
        uint pB = hs[sB * 32 + cl];
        denA += wA;
        aLA += wA * __uint_as_float(pA << 16);
        aHA += wA * __uint_as_float(pA & 0xffff0000u);
        denB += wB;
        aLB += wB * __uint_as_float(pB << 16);
        aHB += wB * __uint_as_float(pB & 0xffff0000u);
    }
    float den = denA + denB, accL = aLA + aLB, accH = aHA + aHB;
    den  += __shfl_xor(den, 32, 64);
    accL += __shfl_xor(accL, 32, 64);
    accH += __shfl_xor(accH, 32, 64);
    if (sub == 0) {
        float inv = 1.f / (den + 1e-16f);
        float o0 = fmaxf(accL * inv + bias[2*cl],     0.f);
        float o1 = fmaxf(accH * inv + bias[2*cl + 1], 0.f);
        *reinterpret_cast<float2*>(&out[(size_t)d * 64 + 2*cl]) = make_float2(o0, o1);
    }
}

// ---------------- layer-2 aggregation: wave per dst, quarter-wave per edge,
// TWO independent edge-chains per lane (8 edges in flight per wave).
// lanes: sub = lane>>4 (0..3), cl = lane&15 (dword = ch pair {2cl,2cl+1}), single head
__global__ __launch_bounds__(256) void gat_agg_l2(
    const int* __restrict__ offs_t, const int* __restrict__ srcs_t,
    const float* __restrict__ als_d_, const float* __restrict__ ald_t,
    const uint* __restrict__ hs_d_, const float* __restrict__ bias_a, float* __restrict__ out_t,
    const int* __restrict__ offs_d, const int* __restrict__ srcs_d,
    const float* __restrict__ als_t, const float* __restrict__ ald_d,
    const uint* __restrict__ hs_t, const float* __restrict__ bias_b, float* __restrict__ out_d)
{
    const int nbT = (NTASK + 3) / 4;
    int wave = threadIdx.x >> 6, lane = threadIdx.x & 63;
    const int* offs; const int* srcs; const float* als; const float* ald;
    const uint* hs; const float* bias; float* out; int Nd, d;
    if ((int)blockIdx.x < nbT) {
        offs = offs_t; srcs = srcs_t; als = als_d_; ald = ald_t; hs = hs_d_;
        bias = bias_a; out = out_t; Nd = NTASK; d = blockIdx.x * 4 + wave;
    } else {
        offs = offs_d; srcs = srcs_d; als = als_t; ald = ald_d; hs = hs_t;
        bias = bias_b; out = out_d; Nd = NDEV; d = ((int)blockIdx.x - nbT) * 4 + wave;
    }
    if (d >= Nd) return;
    int sub = lane >> 4;
    int cl  = lane & 15;
    float aldv = ald[d];
    int beg = __builtin_amdgcn_readfirstlane(offs[d]);
    int end = __builtin_amdgcn_readfirstlane(offs[d + 1]);
    float denA = 0.f, aLA = 0.f, aHA = 0.f;
    float denB = 0.f, aLB = 0.f, aHB = 0.f;
    for (int i0 = beg + sub; i0 < end; i0 += 8) {
        int iB = i0 + 4;
        bool vB = iB < end;
        int sA = srcs[i0];
        int sB = srcs[vB ? iB : beg];
        float eA = als[sA] + aldv; eA = fmaxf(eA, 0.2f * eA);
        float eB = als[sB] + aldv; eB = fmaxf(eB, 0.2f * eB);
        float wA = __expf(eA);
        float wB = vB ? __expf(eB) : 0.f;
        uint pA = hs[sA * 16 + cl];
        uint pB = hs[sB * 16 + cl];
        denA += wA;
        aLA += wA * __uint_as_float(pA << 16);
        aHA += wA * __uint_as_float(pA & 0xffff0000u);
        denB += wB;
        aLB += wB * __uint_as_float(pB << 16);
        aHB += wB * __uint_as_float(pB & 0xffff0000u);
    }
    float den = denA + denB, accL = aLA + aLB, accH = aHA + aHB;
    den  += __shfl_xor(den, 16, 64);  den  += __shfl_xor(den, 32, 64);
    accL += __shfl_xor(accL, 16, 64); accL += __shfl_xor(accL, 32, 64);
    accH += __shfl_xor(accH, 16, 64); accH += __shfl_xor(accH, 32, 64);
    if (lane < 16) {
        float inv = 1.f / (den + 1e-16f);
        float o0 = fmaxf(accL * inv + bias[2*cl],     0.f);
        float o1 = fmaxf(accH * inv + bias[2*cl + 1], 0.f);
        *reinterpret_cast<float2*>(&out[(size_t)d * 32 + 2*cl]) = make_float2(o0, o1);
    }
}

// ---------------- launch
extern "C" void kernel_launch(void* const* d_in, const int* in_sizes, int n_in,
                              void* d_out, int out_size, void* d_ws, size_t ws_size,
                              hipStream_t stream)
{
    const float* x_dev   = (const float*)d_in[0];
    const float* x_task  = (const float*)d_in[1];
    const int* writes_src = (const int*)d_in[2];
    const int* writes_dst = (const int*)d_in[3];
    const int* wb_src     = (const int*)d_in[4];
    const int* wb_dst     = (const int*)d_in[5];
    const float* W1a_src = (const float*)d_in[6],  *W1a_dst = (const float*)d_in[7];
    const float* a1a_src = (const float*)d_in[8],  *a1a_dst = (const float*)d_in[9];
    const float* b1a     = (const float*)d_in[10];
    const float* W1b_src = (const float*)d_in[11], *W1b_dst = (const float*)d_in[12];
    const float* a1b_src = (const float*)d_in[13], *a1b_dst = (const float*)d_in[14];
    const float* b1b     = (const float*)d_in[15];
    const float* W2a_src = (const float*)d_in[16], *W2a_dst = (const float*)d_in[17];
    const float* a2a_src = (const float*)d_in[18], *a2a_dst = (const float*)d_in[19];
    const float* b2a     = (const float*)d_in[20];
    const float* W2b_src = (const float*)d_in[21], *W2b_dst = (const float*)d_in[22];
    const float* a2b_src = (const float*)d_in[23], *a2b_dst = (const float*)d_in[24];
    const float* b2b     = (const float*)d_in[25];

    float* out_dev2  = (float*)d_out;
    float* out_task2 = (float*)d_out + (size_t)NDEV * 32;

    char* ws = (char*)d_ws;
    size_t off = 0;
    auto take = [&](size_t bytes) -> void* {
        off = (off + 255) & ~(size_t)255;
        void* p = ws + off; off += bytes; return p;
    };
    int* s_w       = (int*)take((size_t)NE * 4);
    int* s_b       = (int*)take((size_t)NE * 4);
    int* offs_task = (int*)take((size_t)(NTASK + 1) * 4);
    int* offs_dev  = (int*)take((size_t)(NDEV + 1) * 4);
    int* cnt_task  = (int*)take((size_t)(NTASK + NDEV) * 4);
    int* cnt_dev   = cnt_task + NTASK;
    int* partials  = (int*)take(256 * 4);
    float* Wc_dev1  = (float*)take(64 * 72 * 4);
    float* Wc_task1 = (float*)take(64 * 72 * 4);
    float* Wc_dev2  = (float*)take(64 * 36 * 4);
    float* Wc_task2 = (float*)take(64 * 36 * 4);
    uint* hs_dev    = (uint*)take((size_t)NDEV * 32 * 4);
    float* als_dev  = (float*)take((size_t)NDEV * 4 * 4);
    float* aldx_dev = (float*)take((size_t)NDEV * 4 * 4);
    uint* hs_task   = (uint*)take((size_t)NTASK * 32 * 4);
    float* als_task = (float*)take((size_t)NTASK * 4 * 4);
    float* aldx_task= (float*)take((size_t)NTASK * 4 * 4);
    float* x_task1  = (float*)take((size_t)NTASK * 64 * 4);
    float* x_dev1   = (float*)take((size_t)NDEV * 64 * 4);
    // rank arrays alias x_dev1 (12.8MB >= 8MB): written by edge_rank, consumed by
    // edge_fill2, both strictly before gat_agg_l1 writes x_dev1 (in-order stream).
    int* rank_w = (int*)x_dev1;
    int* rank_b = rank_w + NE;
    (void)ws_size; (void)n_in; (void)in_sizes; (void)out_size;

    hipMemsetAsync(cnt_task, 0, (size_t)(NTASK + NDEV) * 4, stream);

    prep_weights<<<1, 64, 0, stream>>>(
        W1a_src, a1a_src, W1a_dst, a1a_dst, W1b_src, a1b_src, W1b_dst, a1b_dst,
        W2a_src, a2a_src, W2a_dst, a2a_dst, W2b_src, a2b_src, W2b_dst, a2b_dst,
        Wc_dev1, Wc_task1, Wc_dev2, Wc_task2);

    // CSR build (shared by both layers)
    int eg = (2 * NE + 255) / 256;
    edge_rank<<<eg, 256, 0, stream>>>(writes_dst, wb_dst, cnt_task, cnt_dev, rank_w, rank_b);
    scan_tiles<<<NB_T + NB_D, 256, 0, stream>>>(cnt_task, cnt_dev, offs_task, offs_dev, partials);
    scan_partials_k<<<1, 256, 0, stream>>>(partials);
    scan_add<<<NB_T + NB_D, 256, 0, stream>>>(offs_task, offs_dev, partials);
    edge_fill2<<<eg, 256, 0, stream>>>(writes_src, writes_dst, wb_src, wb_dst,
                                       offs_task, offs_dev, rank_w, rank_b, s_w, s_b);

    // layer 1 transforms (both node types, one launch)
    int nb1 = (NDEV + 255) / 256 + (NTASK + 255) / 256;
    gemm_both<72, 64, 4><<<nb1, 256, 0, stream>>>(
        x_dev, NDEV, Wc_dev1, hs_dev, als_dev, aldx_dev,
        x_task, NTASK, Wc_task1, hs_task, als_task, aldx_task);

    // layer 1 aggregation (both directions, one launch)
    int nbagg = (NTASK + 3) / 4 + (NDEV + 3) / 4;
    gat_agg_l1<<<nbagg, 256, 0, stream>>>(
        offs_task, s_w, als_dev, aldx_task, hs_dev, b1a, x_task1,
        offs_dev, s_b, als_task, aldx_dev, hs_task, b1b, x_dev1);

    // layer 2 transforms
    gemm_both<36, 32, 1><<<nb1, 256, 0, stream>>>(
        x_dev1, NDEV, Wc_dev2, hs_dev, als_dev, aldx_dev,
        x_task1, NTASK, Wc_task2, hs_task, als_task, aldx_task);

    // layer 2 aggregation -> final outputs
    gat_agg_l2<<<nbagg, 256, 0, stream>>>(
        offs_task, s_w, als_dev, aldx_task, hs_dev, b2a, out_task2,
        offs_dev, s_b, als_task, aldx_dev, hs_task, b2b, out_dev2);
}